// Round 1
// baseline (90.913 us; speedup 1.0000x reference)
//
#include <hip/hip_runtime.h>
#include <math.h>

#define D 64
#define MAXM 20

// One block (64 threads) per group: masked-mean embedding, dedup flags,
// unique count, and deg[u] scatter.
__global__ void group_init_kernel(const int* __restrict__ membership,
                                  const float* __restrict__ member_mask,
                                  const float* __restrict__ user_emb,
                                  float* __restrict__ emb0,
                                  int* __restrict__ uflag,
                                  int* __restrict__ ucnt,
                                  int* __restrict__ deg) {
  const int g = blockIdx.x;
  const int t = threadIdx.x;            // 0..63 = embedding dim
  __shared__ int   mem[MAXM];
  __shared__ float w[MAXM];
  __shared__ int   uf[MAXM];
  if (t < MAXM) {
    mem[t] = membership[g * MAXM + t];
    w[t]   = expf(member_mask[g * MAXM + t]);
  }
  __syncthreads();

  float acc = 0.f, wsum = 0.f;
#pragma unroll
  for (int m = 0; m < MAXM; ++m) {
    acc  += w[m] * user_emb[(long)mem[m] * D + t];
    wsum += w[m];
  }
  emb0[(long)g * D + t] = acc / wsum;

  if (t < MAXM) {
    int u = mem[t];
    int uniq = 1;
    for (int m = 0; m < t; ++m)
      if (mem[m] == u) uniq = 0;
    uf[t] = uniq;
    uflag[g * MAXM + t] = uniq;
    if (uniq) atomicAdd(&deg[u], 1);
  }
  __syncthreads();
  if (t == 0) {
    int c = 0;
    for (int m = 0; m < MAXM; ++m) c += uf[m];
    ucnt[g] = c;
  }
}

// neigh_member[g] = sum over UNIQUE members u of (deg[u]-1) * U[u]
__global__ void neigh_member_kernel(const int* __restrict__ membership,
                                    const int* __restrict__ uflag,
                                    const int* __restrict__ deg,
                                    const float* __restrict__ user_emb,
                                    float* __restrict__ nm) {
  const int g = blockIdx.x;
  const int t = threadIdx.x;
  __shared__ int   mem[MAXM];
  __shared__ float coef[MAXM];
  if (t < MAXM) {
    int u = membership[g * MAXM + t];
    mem[t]  = u;
    coef[t] = uflag[g * MAXM + t] ? (float)(deg[u] - 1) : 0.f;
  }
  __syncthreads();
  float acc = 0.f;
#pragma unroll
  for (int m = 0; m < MAXM; ++m)
    acc += coef[m] * user_emb[(long)mem[m] * D + t];
  nm[(long)g * D + t] = acc;
}

// s[u] += emb[g] for each unique member u of g  (H^T @ emb)
__global__ void scatter_kernel(const int* __restrict__ membership,
                               const int* __restrict__ uflag,
                               const float* __restrict__ emb,
                               float* __restrict__ s) {
  const int g = blockIdx.x;
  const int t = threadIdx.x;
  __shared__ int mem[MAXM];
  __shared__ int uf[MAXM];
  if (t < MAXM) {
    mem[t] = membership[g * MAXM + t];
    uf[t]  = uflag[g * MAXM + t];
  }
  __syncthreads();
  const float e = emb[(long)g * D + t];
  for (int m = 0; m < MAXM; ++m)
    if (uf[m]) atomicAdd(&s[(long)mem[m] * D + t], e);
}

// neigh_group = H @ s - cnt*emb ; msg = ng + nm ;
// emb_out = l2norm( [emb, msg] @ Wk[k]^T + bk[k] )
__global__ void update_kernel(const int* __restrict__ membership,
                              const int* __restrict__ uflag,
                              const int* __restrict__ ucnt,
                              const float* __restrict__ s,
                              const float* __restrict__ nm,
                              const float* __restrict__ Wk,
                              const float* __restrict__ bk,
                              int k,
                              const float* __restrict__ emb_in,
                              float* __restrict__ emb_out) {
  const int g = blockIdx.x;
  const int t = threadIdx.x;
  __shared__ int   mem[MAXM];
  __shared__ int   uf[MAXM];
  __shared__ float e[D];
  __shared__ float ms[D];
  if (t < MAXM) {
    mem[t] = membership[g * MAXM + t];
    uf[t]  = uflag[g * MAXM + t];
  }
  const float ein = emb_in[(long)g * D + t];
  e[t] = ein;
  __syncthreads();

  float ng = 0.f;
#pragma unroll
  for (int m = 0; m < MAXM; ++m)
    if (uf[m]) ng += s[(long)mem[m] * D + t];
  ng -= (float)ucnt[g] * ein;
  ms[t] = ng + nm[(long)g * D + t];
  __syncthreads();

  const float* Wrow = Wk + ((long)k * D + t) * (2 * D);
  float o = bk[k * D + t];
#pragma unroll
  for (int j = 0; j < D; ++j)
    o += e[j] * Wrow[j] + ms[j] * Wrow[D + j];

  float ss = o * o;
#pragma unroll
  for (int off = 32; off; off >>= 1) ss += __shfl_xor(ss, off);
  const float inv = 1.f / fmaxf(sqrtf(ss), 1e-12f);
  emb_out[(long)g * D + t] = o * inv;
}

// One wave (64 lanes) per batch element: x = ge*ie, 16 shuffle-reduced dots,
// relu, 16->1 dot, sigmoid.
__global__ void final_kernel(const int* __restrict__ groups,
                             const int* __restrict__ items,
                             const float* __restrict__ emb,
                             const float* __restrict__ item_emb,
                             const float* __restrict__ p1w,
                             const float* __restrict__ p1b,
                             const float* __restrict__ p2w,
                             const float* __restrict__ p2b,
                             float* __restrict__ out, int B) {
  const int wave = (blockIdx.x * blockDim.x + threadIdx.x) >> 6;
  const int lane = threadIdx.x & 63;
  if (wave >= B) return;
  const int g  = groups[wave];
  const int it = items[wave];
  const float x = emb[(long)g * D + lane] * item_emb[(long)it * D + lane];
  float acc2 = p2b[0];
#pragma unroll
  for (int j = 0; j < 16; ++j) {
    float p = x * p1w[j * D + lane];
#pragma unroll
    for (int off = 32; off; off >>= 1) p += __shfl_xor(p, off);
    const float h = fmaxf(p + p1b[j], 0.f);
    acc2 += h * p2w[j];
  }
  if (lane == 0) out[wave] = 1.f / (1.f + expf(-acc2));
}

extern "C" void kernel_launch(void* const* d_in, const int* in_sizes, int n_in,
                              void* d_out, int out_size, void* d_ws, size_t ws_size,
                              hipStream_t stream) {
  const int*   groups      = (const int*)d_in[0];
  const int*   items       = (const int*)d_in[1];
  const int*   membership  = (const int*)d_in[2];
  const float* member_mask = (const float*)d_in[3];
  // d_in[4] hyper_graph: NOT needed (sparse identity via membership lists)
  const float* user_emb    = (const float*)d_in[5];
  const float* item_emb    = (const float*)d_in[6];
  const float* Wk          = (const float*)d_in[7];
  const float* bk          = (const float*)d_in[8];
  const float* p1w         = (const float*)d_in[9];
  const float* p1b         = (const float*)d_in[10];
  const float* p2w         = (const float*)d_in[11];
  const float* p2b         = (const float*)d_in[12];
  float* out = (float*)d_out;

  const int B  = in_sizes[0];
  const int G  = in_sizes[2] / MAXM;
  const int NU = in_sizes[5] / D;
  const int K  = in_sizes[7] / (D * 2 * D);

  char* ws = (char*)d_ws;
  float* emb_a = (float*)ws; ws += (size_t)G * D * 4;
  float* emb_b = (float*)ws; ws += (size_t)G * D * 4;
  float* nm    = (float*)ws; ws += (size_t)G * D * 4;
  float* s     = (float*)ws; ws += (size_t)NU * D * 4;
  int*   deg   = (int*)ws;   ws += (size_t)NU * 4;
  int*   uflag = (int*)ws;   ws += (size_t)G * MAXM * 4;
  int*   ucnt  = (int*)ws;   ws += (size_t)G * 4;

  hipMemsetAsync(deg, 0, (size_t)NU * 4, stream);
  group_init_kernel<<<G, 64, 0, stream>>>(membership, member_mask, user_emb,
                                          emb_a, uflag, ucnt, deg);
  neigh_member_kernel<<<G, 64, 0, stream>>>(membership, uflag, deg, user_emb, nm);

  float* cur = emb_a;
  float* nxt = emb_b;
  for (int k = 0; k < K; ++k) {
    hipMemsetAsync(s, 0, (size_t)NU * D * 4, stream);
    scatter_kernel<<<G, 64, 0, stream>>>(membership, uflag, cur, s);
    update_kernel<<<G, 64, 0, stream>>>(membership, uflag, ucnt, s, nm, Wk, bk,
                                        k, cur, nxt);
    float* tmp = cur; cur = nxt; nxt = tmp;
  }

  final_kernel<<<(B * 64 + 255) / 256, 256, 0, stream>>>(
      groups, items, cur, item_emb, p1w, p1b, p2w, p2b, out, B);
}